// Round 12
// baseline (270.828 us; speedup 1.0000x reference)
//
#include <hip/hip_runtime.h>
#include <hip/hip_bf16.h>

// Problem constants (fixed shapes)
#define BATCH 2
#define SEQ   2048
#define EMB   1024
#define DATTN 1024
#define NH    16
#define HD    64
#define MM    (BATCH*SEQ)        // 4096 rows
#define SCALE 0.03125f           // 1/sqrt(1024), exact power of 2
#define MINIT -1.0e30f
#define ROPE_COEF 0.41524101186f // (2/64)*log2(10000)

using bf16x8 = __attribute__((ext_vector_type(8))) short;   // 8 bf16 (4 VGPRs)
using f32x4  = __attribute__((ext_vector_type(4))) float;   // MFMA C/D

__device__ inline short f2bf(float x) {
    __hip_bfloat16 b = __float2bfloat16(x);
    return *reinterpret_cast<short*>(&b);
}
__device__ inline float bf2f(unsigned int u16) {
    union { unsigned int i; float f; } c;
    c.i = u16 << 16;
    return c.f;
}

// async global->LDS, 16 B per lane (wave-uniform LDS base). [m03/m97]
__device__ inline void gl_lds16(const short* g, short* l) {
    __builtin_amdgcn_global_load_lds(
        (const __attribute__((address_space(1))) unsigned int*)g,
        (__attribute__((address_space(3))) unsigned int*)l, 16, 0, 0);
}

// ---------------- fp32 -> bf16 pre-convert (q,k,v,Wq,Wk,Wv,Wo) ----------------
__global__ __launch_bounds__(256)
void cvt_all(const float* __restrict__ q, const float* __restrict__ k,
             const float* __restrict__ v,
             const float* __restrict__ Wq, const float* __restrict__ Wk,
             const float* __restrict__ Wv, const float* __restrict__ Wo,
             short* __restrict__ dst)
{
    const long QKV = (long)MM * EMB;      // 4,194,304
    const long WSZ = (long)DATTN * EMB;   // 1,048,576
    const long i = ((long)blockIdx.x * 256 + threadIdx.x) * 4;
    const float* s;
    long off;
    if (i < 3 * QKV) {
        const int seg = (int)(i / QKV);
        off = i - (long)seg * QKV;
        s = (seg == 0) ? q : (seg == 1) ? k : v;
    } else {
        const long j = i - 3 * QKV;
        const int seg = (int)(j / WSZ);
        off = j - (long)seg * WSZ;
        s = (seg == 0) ? Wq : (seg == 1) ? Wk : (seg == 2) ? Wv : Wo;
    }
    float4 x = *(const float4*)(s + off);
    short4 y;
    y.x = f2bf(x.x); y.y = f2bf(x.y); y.z = f2bf(x.z); y.w = f2bf(x.w);
    *(short4*)(dst + i) = y;
}

// ---------------- bf16 MFMA GEMM: 128x128 tile, BK=32, global_load_lds staging ----------------
__device__ inline void stage_tile(const short* g, short* lds, int wave, int lane) {
    #pragma unroll
    for (int qq = 0; qq < 2; ++qq) {
        const int r = wave * 32 + qq * 16 + (lane >> 2);
        gl_lds16(g + (long)r * EMB + (lane & 3) * 8, lds + (wave * 2 + qq) * 512);
    }
}

// Fused Q/K/V projection with RoPE fused into the epilogue for Q/K.
__global__ __launch_bounds__(256)
void gemm_proj_bf16(const short* __restrict__ qb, const short* __restrict__ kb,
                    const short* __restrict__ vb,
                    const short* __restrict__ wqb, const short* __restrict__ wkb,
                    const short* __restrict__ wvb,
                    short* __restrict__ Qb, short* __restrict__ Kb,
                    short* __restrict__ Vtb)
{
    const short* A; const short* B;
    if (blockIdx.z == 0)      { A = qb; B = wqb; }
    else if (blockIdx.z == 1) { A = kb; B = wkb; }
    else                      { A = vb; B = wvb; }

    __shared__ short sA[128 * 32];
    __shared__ short sB[128 * 32];

    const int tid  = threadIdx.x;
    const int wave = tid >> 6, lane = tid & 63;
    const int quad = lane >> 4, l16 = lane & 15;
    const int wm = (wave >> 1) * 64, wn = (wave & 1) * 64;
    const long m0 = (long)blockIdx.x * 128, n0 = (long)blockIdx.y * 128;

    f32x4 acc[4][4];
    #pragma unroll
    for (int i = 0; i < 4; ++i)
        #pragma unroll
        for (int j = 0; j < 4; ++j) acc[i][j] = (f32x4){0.f, 0.f, 0.f, 0.f};

    for (int kt = 0; kt < EMB; kt += 32) {
        __syncthreads();
        stage_tile(A + m0 * EMB + kt, sA, wave, lane);
        stage_tile(B + n0 * EMB + kt, sB, wave, lane);
        __syncthreads();

        bf16x8 af[4], bfr[4];
        #pragma unroll
        for (int rt = 0; rt < 4; ++rt)
            af[rt] = *(const bf16x8*)&sA[(wm + rt * 16 + l16) * 32 + quad * 8];
        #pragma unroll
        for (int ct = 0; ct < 4; ++ct)
            bfr[ct] = *(const bf16x8*)&sB[(wn + ct * 16 + l16) * 32 + quad * 8];
        #pragma unroll
        for (int rt = 0; rt < 4; ++rt)
            #pragma unroll
            for (int ct = 0; ct < 4; ++ct)
                acc[rt][ct] = __builtin_amdgcn_mfma_f32_16x16x32_bf16(
                    af[rt], bfr[ct], acc[rt][ct], 0, 0, 0);
    }

    if (blockIdx.z < 2) {
        // Q/K: fused RoPE (pair lives in adjacent l16 lanes -> shfl_xor(.,1))
        short* C = (blockIdx.z == 0) ? Qb : Kb;
        const float scl = (blockIdx.z == 0) ? SCALE : 1.0f;
        const int odd = l16 & 1;
        #pragma unroll
        for (int ct = 0; ct < 4; ++ct) {
            const long col = n0 + wn + ct * 16 + l16;
            const int hh = (int)(col >> 6), dd = (int)(col & (HD - 1));
            const float invf = exp2f(-ROPE_COEF * (float)(dd >> 1));
            #pragma unroll
            for (int rt = 0; rt < 4; ++rt) {
                #pragma unroll
                for (int reg = 0; reg < 4; ++reg) {
                    const long row = m0 + wm + rt * 16 + quad * 4 + reg;
                    const int bb = (int)(row >> 11), ss = (int)(row & (SEQ - 1));
                    const float val = acc[rt][ct][reg];
                    const float prt = __shfl_xor(val, 1, 64);
                    float sn, cs;
                    __sincosf((float)ss * invf, &sn, &cs);
                    const float o = odd ? (prt * sn + val * cs)
                                        : (val * cs - prt * sn);
                    C[(((long)(bb * NH + hh)) << 17) + ((long)ss << 6) + dd] =
                        f2bf(o * scl);
                }
            }
        }
    } else {
        // V transposed: Vt[((b*NH+h)*HD + d)*SEQ + s]
        #pragma unroll
        for (int rt = 0; rt < 4; ++rt) {
            #pragma unroll
            for (int ct = 0; ct < 4; ++ct) {
                const long row0 = m0 + wm + rt * 16 + quad * 4;
                const long col  = n0 + wn + ct * 16 + l16;
                const int bb = (int)(row0 >> 11), ss = (int)(row0 & (SEQ - 1));
                const int hh = (int)(col >> 6),   dd = (int)(col & (HD - 1));
                short4 s4;
                s4.x = f2bf(acc[rt][ct][0]); s4.y = f2bf(acc[rt][ct][1]);
                s4.z = f2bf(acc[rt][ct][2]); s4.w = f2bf(acc[rt][ct][3]);
                *(short4*)&Vtb[(((long)(bb * NH + hh)) << 17) + ((long)dd << 11) + ss] = s4;
            }
        }
    }
}

// Output GEMM: out = ctx(bf16) @ Wo^T(bf16), out fp32 [4096,1024]
__global__ __launch_bounds__(256)
void gemm_out_bf16(const short* __restrict__ Ab, const short* __restrict__ Bb,
                   float* __restrict__ C)
{
    __shared__ short sA[128 * 32];
    __shared__ short sB[128 * 32];

    const int tid  = threadIdx.x;
    const int wave = tid >> 6, lane = tid & 63;
    const int quad = lane >> 4, l16 = lane & 15;
    const int wm = (wave >> 1) * 64, wn = (wave & 1) * 64;
    const long m0 = (long)blockIdx.x * 128, n0 = (long)blockIdx.y * 128;

    f32x4 acc[4][4];
    #pragma unroll
    for (int i = 0; i < 4; ++i)
        #pragma unroll
        for (int j = 0; j < 4; ++j) acc[i][j] = (f32x4){0.f, 0.f, 0.f, 0.f};

    for (int kt = 0; kt < DATTN; kt += 32) {
        __syncthreads();
        stage_tile(Ab + m0 * DATTN + kt, sA, wave, lane);
        stage_tile(Bb + n0 * DATTN + kt, sB, wave, lane);
        __syncthreads();

        bf16x8 af[4], bfr[4];
        #pragma unroll
        for (int rt = 0; rt < 4; ++rt)
            af[rt] = *(const bf16x8*)&sA[(wm + rt * 16 + l16) * 32 + quad * 8];
        #pragma unroll
        for (int ct = 0; ct < 4; ++ct)
            bfr[ct] = *(const bf16x8*)&sB[(wn + ct * 16 + l16) * 32 + quad * 8];
        #pragma unroll
        for (int rt = 0; rt < 4; ++rt)
            #pragma unroll
            for (int ct = 0; ct < 4; ++ct)
                acc[rt][ct] = __builtin_amdgcn_mfma_f32_16x16x32_bf16(
                    af[rt], bfr[ct], acc[rt][ct], 0, 0, 0);
    }

    #pragma unroll
    for (int rt = 0; rt < 4; ++rt) {
        #pragma unroll
        for (int ct = 0; ct < 4; ++ct) {
            #pragma unroll
            for (int reg = 0; reg < 4; ++reg) {
                const long row = m0 + wm + rt * 16 + quad * 4 + reg;
                const long col = n0 + wn + ct * 16 + l16;
                C[row * EMB + col] = acc[rt][ct][reg];
            }
        }
    }
}

// ---------------- MFMA flash attention, SPLIT-K over the key range ----------------
// Block = (b, h, 128-query tile, split sc). split0: 64-key tiles [0, t+1),
// split1: [t+1, 2t+2) -> max 16 rounds per block (was 32 serial for t=15).
// 1024 equal-ish blocks, 27.6 KB LDS -> 4 blocks/CU co-resident.
// Writes UNNORMALIZED O (bf16) + per-query (m, l) fp32; combine kernel merges.
// S^T formulation (R9-verified body). mask: j < i, (0,0) allowed.
#define LDP 72

__global__ __launch_bounds__(256, 1)
void flash_attn_split(const short* __restrict__ Qb,
                      const short* __restrict__ Kb,
                      const short* __restrict__ Vtb,
                      short* __restrict__ Opart,
                      float2* __restrict__ mlbuf)
{
    const int t  = (SEQ / 128) - 1 - blockIdx.x;   // heavy tiles first
    const int h  = blockIdx.y;
    const int b  = blockIdx.z & 1, sc = blockIdx.z >> 1;
    const int tid = threadIdx.x;
    const int wave = tid >> 6, lane = tid & 63;
    const int quad = lane >> 4, l16 = lane & 15;
    const int r0 = t * 128;

    __shared__ short sk[64 * LDP];
    __shared__ short sv[64 * LDP];
    __shared__ short sp[4][16 * LDP];

    const long base = ((long)(b * NH + h)) << 17;   // SEQ*HD = 2^17

    // Q fragments (B operand): row l16 = query, k = quad*8 (+tt*32)
    bf16x8 qf[2][2];
    #pragma unroll
    for (int g = 0; g < 2; ++g)
        #pragma unroll
        for (int tt = 0; tt < 2; ++tt)
            qf[g][tt] = *(const bf16x8*)(Qb + base
                + (long)(r0 + 64 * g + wave * 16 + l16) * HD + tt * 32 + quad * 8);

    f32x4 acc_o[2][4];
    #pragma unroll
    for (int g = 0; g < 2; ++g)
        #pragma unroll
        for (int ct = 0; ct < 4; ++ct) acc_o[g][ct] = (f32x4){0.f, 0.f, 0.f, 0.f};
    float mq[2] = {MINIT, MINIT};
    float lq[2] = {0.f, 0.f};

    const int startT = sc ? (t + 1) : 0;        // 64-key tile range for this split
    const int endT   = sc ? (2 * t + 2) : (t + 1);

    #pragma unroll 1
    for (int jt2 = startT; jt2 < endT; ++jt2) {
        const int jbase = jt2 * 64;

        __syncthreads();   // protect previous-iteration sk/sv reads
        #pragma unroll
        for (int c = 0; c < 2; ++c) {
            int cc  = c * 256 + tid;          // 0..511
            int row = cc >> 3;                // 0..63
            int off = (cc & 7) * 8;           // 0..56
            int4 tK = *(const int4*)(Kb + base + (long)(jbase + row) * HD + off);
            *(int4*)&sk[row * LDP + off] = tK;
            int4 tV = *(const int4*)(Vtb + base + ((long)row << 11) + jbase + off);
            *(int4*)&sv[row * LDP + off] = tV;
        }
        __syncthreads();

        bf16x8 kf[4][2], vf[4][2];
        #pragma unroll
        for (int ct = 0; ct < 4; ++ct) {
            kf[ct][0] = *(const bf16x8*)&sk[(ct * 16 + l16) * LDP + quad * 8];
            kf[ct][1] = *(const bf16x8*)&sk[(ct * 16 + l16) * LDP + 32 + quad * 8];
            vf[ct][0] = *(const bf16x8*)&sv[(ct * 16 + l16) * LDP + quad * 8];
            vf[ct][1] = *(const bf16x8*)&sv[(ct * 16 + l16) * LDP + 32 + quad * 8];
        }

        short* pw = sp[wave];

        #pragma unroll
        for (int g = 0; g < 2; ++g) {
            if (g == 0 && jt2 == 2 * t + 1) continue;   // fully masked

            f32x4 s[4];
            #pragma unroll
            for (int ct = 0; ct < 4; ++ct) {
                f32x4 z = (f32x4){0.f, 0.f, 0.f, 0.f};
                z = __builtin_amdgcn_mfma_f32_16x16x32_bf16(kf[ct][0], qf[g][0], z, 0, 0, 0);
                z = __builtin_amdgcn_mfma_f32_16x16x32_bf16(kf[ct][1], qf[g][1], z, 0, 0, 0);
                s[ct] = z;
            }

            const int iq = r0 + 64 * g + wave * 16 + l16;
            if (jt2 == 2 * t + g) {   // only tile that can violate j < i
                #pragma unroll
                for (int ct = 0; ct < 4; ++ct)
                    #pragma unroll
                    for (int r = 0; r < 4; ++r) {
                        const int j = jbase + ct * 16 + quad * 4 + r;
                        const bool ok = (j < iq) || (iq == 0 && j == 0);
                        if (!ok) s[ct][r] = -INFINITY;
                    }
            }

            float mx = MINIT;
            #pragma unroll
            for (int ct = 0; ct < 4; ++ct)
                #pragma unroll
                for (int r = 0; r < 4; ++r) mx = fmaxf(mx, s[ct][r]);
            mx = fmaxf(mx, __shfl_xor(mx, 16, 64));
            mx = fmaxf(mx, __shfl_xor(mx, 32, 64));
            const float mn = fmaxf(mq[g], mx);
            const float alpha = __expf(mq[g] - mn);
            mq[g] = mn;
            float ss = 0.f;
            #pragma unroll
            for (int ct = 0; ct < 4; ++ct)
                #pragma unroll
                for (int r = 0; r < 4; ++r) {
                    const float e = __expf(s[ct][r] - mn);
                    s[ct][r] = e;
                    ss += e;
                }
            ss += __shfl_xor(ss, 16, 64);
            ss += __shfl_xor(ss, 32, 64);
            lq[g] = lq[g] * alpha + ss;

            #pragma unroll
            for (int ct = 0; ct < 4; ++ct) {
                short4 p4;
                p4.x = f2bf(s[ct][0]); p4.y = f2bf(s[ct][1]);
                p4.z = f2bf(s[ct][2]); p4.w = f2bf(s[ct][3]);
                *(short4*)&pw[l16 * LDP + ct * 16 + quad * 4] = p4;
            }

            #pragma unroll
            for (int ct = 0; ct < 4; ++ct)
                #pragma unroll
                for (int r = 0; r < 4; ++r) acc_o[g][ct][r] *= alpha;

            bf16x8 pf0 = *(const bf16x8*)&pw[l16 * LDP + quad * 8];
            bf16x8 pf1 = *(const bf16x8*)&pw[l16 * LDP + 32 + quad * 8];
            #pragma unroll
            for (int ct = 0; ct < 4; ++ct) {
                acc_o[g][ct] = __builtin_amdgcn_mfma_f32_16x16x32_bf16(
                    vf[ct][0], pf0, acc_o[g][ct], 0, 0, 0);
                acc_o[g][ct] = __builtin_amdgcn_mfma_f32_16x16x32_bf16(
                    vf[ct][1], pf1, acc_o[g][ct], 0, 0, 0);
            }
        }
    }

    // epilogue: UNNORMALIZED partials. Opart[(sc*2+b)*NH+h][iq][d] bf16 + (m,l) fp32
    const long obase = (((long)((sc * BATCH + b) * NH + h)) << 17);
    #pragma unroll
    for (int g = 0; g < 2; ++g) {
        const int iq = r0 + 64 * g + wave * 16 + l16;
        short* orow = Opart + obase + (long)iq * HD;
        #pragma unroll
        for (int ct = 0; ct < 4; ++ct) {
            short4 o4;
            o4.x = f2bf(acc_o[g][ct][0]);
            o4.y = f2bf(acc_o[g][ct][1]);
            o4.z = f2bf(acc_o[g][ct][2]);
            o4.w = f2bf(acc_o[g][ct][3]);
            *(short4*)&orow[ct * 16 + quad * 4] = o4;
        }
        if (quad == 0) {
            float2 ml; ml.x = mq[g]; ml.y = lq[g];
            mlbuf[((sc * BATCH + b) * NH + h) * SEQ + iq] = ml;
        }
    }
}

// ---------------- combine: merge the two splits' partial softmax results ----------------
__global__ __launch_bounds__(256)
void attn_combine(const short* __restrict__ Opart, const float2* __restrict__ mlbuf,
                  short* __restrict__ ctx)
{
    const int idx = blockIdx.x * 256 + threadIdx.x;   // < 1,048,576
    const int d4g = idx & 15;
    const int row = idx >> 4;                          // (b*NH+h)*SEQ + iq
    const float2 ml0 = mlbuf[row];
    const float2 ml1 = mlbuf[row + BATCH * NH * SEQ];
    const float ms = fmaxf(ml0.x, ml1.x);
    float r0 = __expf(ml0.x - ms), r1 = __expf(ml1.x - ms);
    const float inv = 1.f / (ml0.y * r0 + ml1.y * r1);
    r0 *= inv; r1 *= inv;
    const long ob = (long)row * HD + d4g * 4;
    const short4 a = *(const short4*)&Opart[ob];
    const short4 c = *(const short4*)&Opart[ob + (long)BATCH * NH * SEQ * HD];
    short4 o;
    o.x = f2bf(bf2f((unsigned short)a.x) * r0 + bf2f((unsigned short)c.x) * r1);
    o.y = f2bf(bf2f((unsigned short)a.y) * r0 + bf2f((unsigned short)c.y) * r1);
    o.z = f2bf(bf2f((unsigned short)a.z) * r0 + bf2f((unsigned short)c.z) * r1);
    o.w = f2bf(bf2f((unsigned short)a.w) * r0 + bf2f((unsigned short)c.w) * r1);
    const int bb = row >> 15, hh = (row >> 11) & 15, iq = row & (SEQ - 1);
    *(short4*)&ctx[((long)(bb * SEQ + iq)) * DATTN + hh * HD + d4g * 4] = o;
}

extern "C" void kernel_launch(void* const* d_in, const int* in_sizes, int n_in,
                              void* d_out, int out_size, void* d_ws, size_t ws_size,
                              hipStream_t stream) {
    const float* q  = (const float*)d_in[0];
    const float* k  = (const float*)d_in[1];
    const float* v  = (const float*)d_in[2];
    const float* Wq = (const float*)d_in[3];
    const float* Wk = (const float*)d_in[4];
    const float* Wv = (const float*)d_in[5];
    const float* Wo = (const float*)d_in[6];
    float* out = (float*)d_out;

    // workspace (bf16 shorts), 64 MB:
    // qb|kb|vb (4M shorts each) | wqb|wkb|wvb|wob (1M each) | Qb|Kb|Vtb|ctx (4M each)
    // After proj: qb+kb region reused as Opart (8.4M shorts), wqb reused as mlbuf.
    const long QKV = (long)MM * EMB;      // 4,194,304
    const long WSZ = (long)DATTN * EMB;   // 1,048,576
    short* basep = (short*)d_ws;
    short* qb  = basep;
    short* kb  = qb + QKV;
    short* vb  = kb + QKV;
    short* wqb = vb + QKV;
    short* wkb = wqb + WSZ;
    short* wvb = wkb + WSZ;
    short* wob = wvb + WSZ;
    short* Qb  = wob + WSZ;
    short* Kb  = Qb + QKV;
    short* Vtb = Kb + QKV;
    short* ctx = Vtb + QKV;
    short* Opart = qb;                    // 2 x 4,194,304 shorts (fits qb+kb)
    float2* mlbuf = (float2*)wqb;         // 131072 float2 = 1 MB (fits wqb)

    // 1) fp32 -> bf16 pre-convert
    cvt_all<<<16384, 256, 0, stream>>>(q, k, v, Wq, Wk, Wv, Wo, qb);

    // 2) fused Q/K/V projection + RoPE
    gemm_proj_bf16<<<dim3(MM / 128, DATTN / 128, 3), 256, 0, stream>>>(
        qb, kb, vb, wqb, wkb, wvb, Qb, Kb, Vtb);

    // 3) flash attention, split-K=2 (z = sc*2 + b)
    flash_attn_split<<<dim3(SEQ / 128, NH, 4), 256, 0, stream>>>(
        Qb, Kb, Vtb, Opart, mlbuf);

    // 4) combine splits -> ctx
    attn_combine<<<4096, 256, 0, stream>>>(Opart, mlbuf, ctx);

    // 5) output GEMM
    gemm_out_bf16<<<dim3(MM / 128, EMB / 128), 256, 0, stream>>>(ctx, wob, out);
}

// Round 13
// 248.294 us; speedup vs baseline: 1.0908x; 1.0908x over previous
//
#include <hip/hip_runtime.h>
#include <hip/hip_bf16.h>

// Problem constants (fixed shapes)
#define BATCH 2
#define SEQ   2048
#define EMB   1024
#define DATTN 1024
#define NH    16
#define HD    64
#define MM    (BATCH*SEQ)        // 4096 rows
#define SCALE 0.03125f           // 1/sqrt(1024), exact power of 2
#define MINIT -1.0e30f
#define ROPE_COEF 0.41524101186f // (2/64)*log2(10000)

using bf16x8 = __attribute__((ext_vector_type(8))) short;   // 8 bf16 (4 VGPRs)
using f32x4  = __attribute__((ext_vector_type(4))) float;   // MFMA C/D

__device__ inline short f2bf(float x) {
    __hip_bfloat16 b = __float2bfloat16(x);
    return *reinterpret_cast<short*>(&b);
}

// async global->LDS, 16 B per lane (wave-uniform LDS base). [m03/m97]
__device__ inline void gl_lds16(const short* g, short* l) {
    __builtin_amdgcn_global_load_lds(
        (const __attribute__((address_space(1))) unsigned int*)g,
        (__attribute__((address_space(3))) unsigned int*)l, 16, 0, 0);
}

// ---------------- fp32 -> bf16 pre-convert (q,k,v,Wq,Wk,Wv,Wo) ----------------
__global__ __launch_bounds__(256)
void cvt_all(const float* __restrict__ q, const float* __restrict__ k,
             const float* __restrict__ v,
             const float* __restrict__ Wq, const float* __restrict__ Wk,
             const float* __restrict__ Wv, const float* __restrict__ Wo,
             short* __restrict__ dst)
{
    const long QKV = (long)MM * EMB;      // 4,194,304
    const long WSZ = (long)DATTN * EMB;   // 1,048,576
    const long i = ((long)blockIdx.x * 256 + threadIdx.x) * 4;
    const float* s;
    long off;
    if (i < 3 * QKV) {
        const int seg = (int)(i / QKV);
        off = i - (long)seg * QKV;
        s = (seg == 0) ? q : (seg == 1) ? k : v;
    } else {
        const long j = i - 3 * QKV;
        const int seg = (int)(j / WSZ);
        off = j - (long)seg * WSZ;
        s = (seg == 0) ? Wq : (seg == 1) ? Wk : (seg == 2) ? Wv : Wo;
    }
    float4 x = *(const float4*)(s + off);
    short4 y;
    y.x = f2bf(x.x); y.y = f2bf(x.y); y.z = f2bf(x.z); y.w = f2bf(x.w);
    *(short4*)(dst + i) = y;
}

// ---------------- bf16 MFMA GEMM: 128x128 tile, BK=32, global_load_lds staging ----------------
__device__ inline void stage_tile(const short* g, short* lds, int wave, int lane) {
    #pragma unroll
    for (int qq = 0; qq < 2; ++qq) {
        const int r = wave * 32 + qq * 16 + (lane >> 2);
        gl_lds16(g + (long)r * EMB + (lane & 3) * 8, lds + (wave * 2 + qq) * 512);
    }
}

// Fused Q/K/V projection with RoPE fused into the epilogue for Q/K.
__global__ __launch_bounds__(256)
void gemm_proj_bf16(const short* __restrict__ qb, const short* __restrict__ kb,
                    const short* __restrict__ vb,
                    const short* __restrict__ wqb, const short* __restrict__ wkb,
                    const short* __restrict__ wvb,
                    short* __restrict__ Qb, short* __restrict__ Kb,
                    short* __restrict__ Vtb)
{
    const short* A; const short* B;
    if (blockIdx.z == 0)      { A = qb; B = wqb; }
    else if (blockIdx.z == 1) { A = kb; B = wkb; }
    else                      { A = vb; B = wvb; }

    __shared__ short sA[128 * 32];
    __shared__ short sB[128 * 32];

    const int tid  = threadIdx.x;
    const int wave = tid >> 6, lane = tid & 63;
    const int quad = lane >> 4, l16 = lane & 15;
    const int wm = (wave >> 1) * 64, wn = (wave & 1) * 64;
    const long m0 = (long)blockIdx.x * 128, n0 = (long)blockIdx.y * 128;

    f32x4 acc[4][4];
    #pragma unroll
    for (int i = 0; i < 4; ++i)
        #pragma unroll
        for (int j = 0; j < 4; ++j) acc[i][j] = (f32x4){0.f, 0.f, 0.f, 0.f};

    for (int kt = 0; kt < EMB; kt += 32) {
        __syncthreads();
        stage_tile(A + m0 * EMB + kt, sA, wave, lane);
        stage_tile(B + n0 * EMB + kt, sB, wave, lane);
        __syncthreads();

        bf16x8 af[4], bfr[4];
        #pragma unroll
        for (int rt = 0; rt < 4; ++rt)
            af[rt] = *(const bf16x8*)&sA[(wm + rt * 16 + l16) * 32 + quad * 8];
        #pragma unroll
        for (int ct = 0; ct < 4; ++ct)
            bfr[ct] = *(const bf16x8*)&sB[(wn + ct * 16 + l16) * 32 + quad * 8];
        #pragma unroll
        for (int rt = 0; rt < 4; ++rt)
            #pragma unroll
            for (int ct = 0; ct < 4; ++ct)
                acc[rt][ct] = __builtin_amdgcn_mfma_f32_16x16x32_bf16(
                    af[rt], bfr[ct], acc[rt][ct], 0, 0, 0);
    }

    if (blockIdx.z < 2) {
        // Q/K: fused RoPE (pair lives in adjacent l16 lanes -> shfl_xor(.,1))
        short* C = (blockIdx.z == 0) ? Qb : Kb;
        const float scl = (blockIdx.z == 0) ? SCALE : 1.0f;
        const int odd = l16 & 1;
        #pragma unroll
        for (int ct = 0; ct < 4; ++ct) {
            const long col = n0 + wn + ct * 16 + l16;
            const int hh = (int)(col >> 6), dd = (int)(col & (HD - 1));
            const float invf = exp2f(-ROPE_COEF * (float)(dd >> 1));
            #pragma unroll
            for (int rt = 0; rt < 4; ++rt) {
                #pragma unroll
                for (int reg = 0; reg < 4; ++reg) {
                    const long row = m0 + wm + rt * 16 + quad * 4 + reg;
                    const int bb = (int)(row >> 11), ss = (int)(row & (SEQ - 1));
                    const float val = acc[rt][ct][reg];
                    const float prt = __shfl_xor(val, 1, 64);
                    float sn, cs;
                    __sincosf((float)ss * invf, &sn, &cs);
                    const float o = odd ? (prt * sn + val * cs)
                                        : (val * cs - prt * sn);
                    C[(((long)(bb * NH + hh)) << 17) + ((long)ss << 6) + dd] =
                        f2bf(o * scl);
                }
            }
        }
    } else {
        // V transposed: Vt[((b*NH+h)*HD + d)*SEQ + s]
        #pragma unroll
        for (int rt = 0; rt < 4; ++rt) {
            #pragma unroll
            for (int ct = 0; ct < 4; ++ct) {
                const long row0 = m0 + wm + rt * 16 + quad * 4;
                const long col  = n0 + wn + ct * 16 + l16;
                const int bb = (int)(row0 >> 11), ss = (int)(row0 & (SEQ - 1));
                const int hh = (int)(col >> 6),   dd = (int)(col & (HD - 1));
                short4 s4;
                s4.x = f2bf(acc[rt][ct][0]); s4.y = f2bf(acc[rt][ct][1]);
                s4.z = f2bf(acc[rt][ct][2]); s4.w = f2bf(acc[rt][ct][3]);
                *(short4*)&Vtb[(((long)(bb * NH + hh)) << 17) + ((long)dd << 11) + ss] = s4;
            }
        }
    }
}

// Output GEMM: out = ctx(bf16) @ Wo^T(bf16), out fp32 [4096,1024]
__global__ __launch_bounds__(256)
void gemm_out_bf16(const short* __restrict__ Ab, const short* __restrict__ Bb,
                   float* __restrict__ C)
{
    __shared__ short sA[128 * 32];
    __shared__ short sB[128 * 32];

    const int tid  = threadIdx.x;
    const int wave = tid >> 6, lane = tid & 63;
    const int quad = lane >> 4, l16 = lane & 15;
    const int wm = (wave >> 1) * 64, wn = (wave & 1) * 64;
    const long m0 = (long)blockIdx.x * 128, n0 = (long)blockIdx.y * 128;

    f32x4 acc[4][4];
    #pragma unroll
    for (int i = 0; i < 4; ++i)
        #pragma unroll
        for (int j = 0; j < 4; ++j) acc[i][j] = (f32x4){0.f, 0.f, 0.f, 0.f};

    for (int kt = 0; kt < DATTN; kt += 32) {
        __syncthreads();
        stage_tile(Ab + m0 * DATTN + kt, sA, wave, lane);
        stage_tile(Bb + n0 * DATTN + kt, sB, wave, lane);
        __syncthreads();

        bf16x8 af[4], bfr[4];
        #pragma unroll
        for (int rt = 0; rt < 4; ++rt)
            af[rt] = *(const bf16x8*)&sA[(wm + rt * 16 + l16) * 32 + quad * 8];
        #pragma unroll
        for (int ct = 0; ct < 4; ++ct)
            bfr[ct] = *(const bf16x8*)&sB[(wn + ct * 16 + l16) * 32 + quad * 8];
        #pragma unroll
        for (int rt = 0; rt < 4; ++rt)
            #pragma unroll
            for (int ct = 0; ct < 4; ++ct)
                acc[rt][ct] = __builtin_amdgcn_mfma_f32_16x16x32_bf16(
                    af[rt], bfr[ct], acc[rt][ct], 0, 0, 0);
    }

    #pragma unroll
    for (int rt = 0; rt < 4; ++rt) {
        #pragma unroll
        for (int ct = 0; ct < 4; ++ct) {
            #pragma unroll
            for (int reg = 0; reg < 4; ++reg) {
                const long row = m0 + wm + rt * 16 + quad * 4 + reg;
                const long col = n0 + wn + ct * 16 + l16;
                C[row * EMB + col] = acc[rt][ct][reg];
            }
        }
    }
}

// ---------------- MFMA flash attention (S^T, TJ=128 staging, XCD-pinned) ----------------
// 1-D grid of 512 blocks. Decode keeps all 16 query-tile blocks of one
// (b,h) pair in the same id%8 residue class -> same XCD under the HW's
// round-robin workgroup dispatch -> that pair's 512 KB K/V stays in one
// 4 MB L2 (4 pairs/XCD = 2 MB working set). Perf heuristic only.
#define LDP 72

__global__ __launch_bounds__(256, 1)
void flash_attn_mfma(const short* __restrict__ Qb,
                     const short* __restrict__ Kb,
                     const short* __restrict__ Vtb,
                     short* __restrict__ ctx)
{
    // id -> (xcd residue r, pair p, query tile t)
    const int id = blockIdx.x;            // 0..511
    const int r  = id & 7;
    const int q8 = id >> 3;               // 0..63
    const int ts = q8 & 15;               // 16 t-slots
    const int pi = q8 >> 4;               // 4 pairs per residue
    const int p  = r + 8 * pi;            // (b*NH+h) in [0,32)
    const int b  = p >> 4, h = p & 15;
    const int t  = 15 - ts;               // heavy tiles dispatched first
    const int tid = threadIdx.x;
    const int wave = tid >> 6, lane = tid & 63;
    const int quad = lane >> 4, l16 = lane & 15;
    const int r0 = t * 128;

    __shared__ short sk2[2][64 * LDP];
    __shared__ short sv2[2][64 * LDP];
    __shared__ short sp[4][16 * LDP];

    const long base = ((long)(b * NH + h)) << 17;   // SEQ*HD = 2^17

    bf16x8 qf[2][2];
    #pragma unroll
    for (int g = 0; g < 2; ++g)
        #pragma unroll
        for (int tt = 0; tt < 2; ++tt)
            qf[g][tt] = *(const bf16x8*)(Qb + base
                + (long)(r0 + 64 * g + wave * 16 + l16) * HD + tt * 32 + quad * 8);

    f32x4 acc_o[2][4];
    #pragma unroll
    for (int g = 0; g < 2; ++g)
        #pragma unroll
        for (int ct = 0; ct < 4; ++ct) acc_o[g][ct] = (f32x4){0.f, 0.f, 0.f, 0.f};
    float mq[2] = {MINIT, MINIT};
    float lq[2] = {0.f, 0.f};

    const int njt = t + 1;     // 128-key tiles

    #pragma unroll 1
    for (int jt = 0; jt < njt; ++jt) {
        const int jbase = jt * 128;

        __syncthreads();   // protect previous-iteration sk2/sv2 reads
        #pragma unroll
        for (int c = 0; c < 4; ++c) {
            int cc   = c * 256 + tid;         // 0..1023
            int half = cc >> 9;               // 0..1
            int row  = (cc >> 3) & 63;        // 0..63
            int off  = (cc & 7) * 8;          // 0..56
            int4 tK = *(const int4*)(Kb + base
                + (long)(jbase + half * 64 + row) * HD + off);
            *(int4*)&sk2[half][row * LDP + off] = tK;
            int4 tV = *(const int4*)(Vtb + base
                + ((long)row << 11) + jbase + half * 64 + off);
            *(int4*)&sv2[half][row * LDP + off] = tV;
        }
        __syncthreads();

        #pragma unroll
        for (int half = 0; half < 2; ++half) {
            const int jb2 = jbase + half * 64;
            const int jt2 = 2 * jt + half;    // 64-key tile index
            const short* skh = sk2[half];
            const short* svh = sv2[half];

            bf16x8 kf[4][2], vf[4][2];
            #pragma unroll
            for (int ct = 0; ct < 4; ++ct) {
                kf[ct][0] = *(const bf16x8*)&skh[(ct * 16 + l16) * LDP + quad * 8];
                kf[ct][1] = *(const bf16x8*)&skh[(ct * 16 + l16) * LDP + 32 + quad * 8];
                vf[ct][0] = *(const bf16x8*)&svh[(ct * 16 + l16) * LDP + quad * 8];
                vf[ct][1] = *(const bf16x8*)&svh[(ct * 16 + l16) * LDP + 32 + quad * 8];
            }

            short* pw = sp[wave];

            #pragma unroll
            for (int g = 0; g < 2; ++g) {
                if (g == 0 && jt2 == 2 * t + 1) continue;   // fully masked

                f32x4 s[4];
                #pragma unroll
                for (int ct = 0; ct < 4; ++ct) {
                    f32x4 z = (f32x4){0.f, 0.f, 0.f, 0.f};
                    z = __builtin_amdgcn_mfma_f32_16x16x32_bf16(kf[ct][0], qf[g][0], z, 0, 0, 0);
                    z = __builtin_amdgcn_mfma_f32_16x16x32_bf16(kf[ct][1], qf[g][1], z, 0, 0, 0);
                    s[ct] = z;
                }

                const int iq = r0 + 64 * g + wave * 16 + l16;
                if (jt2 == 2 * t + g) {   // only tile that can violate j < i
                    #pragma unroll
                    for (int ct = 0; ct < 4; ++ct)
                        #pragma unroll
                        for (int rr = 0; rr < 4; ++rr) {
                            const int j = jb2 + ct * 16 + quad * 4 + rr;
                            const bool ok = (j < iq) || (iq == 0 && j == 0);
                            if (!ok) s[ct][rr] = -INFINITY;
                        }
                }

                float mx = MINIT;
                #pragma unroll
                for (int ct = 0; ct < 4; ++ct)
                    #pragma unroll
                    for (int rr = 0; rr < 4; ++rr) mx = fmaxf(mx, s[ct][rr]);
                mx = fmaxf(mx, __shfl_xor(mx, 16, 64));
                mx = fmaxf(mx, __shfl_xor(mx, 32, 64));
                const float mn = fmaxf(mq[g], mx);
                const float alpha = __expf(mq[g] - mn);
                mq[g] = mn;
                float ss = 0.f;
                #pragma unroll
                for (int ct = 0; ct < 4; ++ct)
                    #pragma unroll
                    for (int rr = 0; rr < 4; ++rr) {
                        const float e = __expf(s[ct][rr] - mn);
                        s[ct][rr] = e;
                        ss += e;
                    }
                ss += __shfl_xor(ss, 16, 64);
                ss += __shfl_xor(ss, 32, 64);
                lq[g] = lq[g] * alpha + ss;

                #pragma unroll
                for (int ct = 0; ct < 4; ++ct) {
                    short4 p4;
                    p4.x = f2bf(s[ct][0]); p4.y = f2bf(s[ct][1]);
                    p4.z = f2bf(s[ct][2]); p4.w = f2bf(s[ct][3]);
                    *(short4*)&pw[l16 * LDP + ct * 16 + quad * 4] = p4;
                }

                #pragma unroll
                for (int ct = 0; ct < 4; ++ct)
                    #pragma unroll
                    for (int rr = 0; rr < 4; ++rr) acc_o[g][ct][rr] *= alpha;

                bf16x8 pf0 = *(const bf16x8*)&pw[l16 * LDP + quad * 8];
                bf16x8 pf1 = *(const bf16x8*)&pw[l16 * LDP + 32 + quad * 8];
                #pragma unroll
                for (int ct = 0; ct < 4; ++ct) {
                    acc_o[g][ct] = __builtin_amdgcn_mfma_f32_16x16x32_bf16(
                        vf[ct][0], pf0, acc_o[g][ct], 0, 0, 0);
                    acc_o[g][ct] = __builtin_amdgcn_mfma_f32_16x16x32_bf16(
                        vf[ct][1], pf1, acc_o[g][ct], 0, 0, 0);
                }
            }
        }
    }

    #pragma unroll
    for (int g = 0; g < 2; ++g) {
        const float inv = 1.f / lq[g];
        const int iq = r0 + 64 * g + wave * 16 + l16;
        short* orow = ctx + (long)(b * SEQ + iq) * DATTN + h * HD;
        #pragma unroll
        for (int ct = 0; ct < 4; ++ct) {
            short4 o4;
            o4.x = f2bf(acc_o[g][ct][0] * inv);
            o4.y = f2bf(acc_o[g][ct][1] * inv);
            o4.z = f2bf(acc_o[g][ct][2] * inv);
            o4.w = f2bf(acc_o[g][ct][3] * inv);
            *(short4*)&orow[ct * 16 + quad * 4] = o4;
        }
    }
}

extern "C" void kernel_launch(void* const* d_in, const int* in_sizes, int n_in,
                              void* d_out, int out_size, void* d_ws, size_t ws_size,
                              hipStream_t stream) {
    const float* q  = (const float*)d_in[0];
    const float* k  = (const float*)d_in[1];
    const float* v  = (const float*)d_in[2];
    const float* Wq = (const float*)d_in[3];
    const float* Wk = (const float*)d_in[4];
    const float* Wv = (const float*)d_in[5];
    const float* Wo = (const float*)d_in[6];
    float* out = (float*)d_out;

    // workspace (bf16 shorts), 64 MB:
    // qb|kb|vb (4M shorts each) | wqb|wkb|wvb|wob (1M each) | Qb|Kb|Vtb|ctx (4M each)
    const long QKV = (long)MM * EMB;      // 4,194,304
    const long WSZ = (long)DATTN * EMB;   // 1,048,576
    short* basep = (short*)d_ws;
    short* qb  = basep;
    short* kb  = qb + QKV;
    short* vb  = kb + QKV;
    short* wqb = vb + QKV;
    short* wkb = wqb + WSZ;
    short* wvb = wkb + WSZ;
    short* wob = wvb + WSZ;
    short* Qb  = wob + WSZ;
    short* Kb  = Qb + QKV;
    short* Vtb = Kb + QKV;
    short* ctx = Vtb + QKV;

    // 1) fp32 -> bf16 pre-convert
    cvt_all<<<16384, 256, 0, stream>>>(q, k, v, Wq, Wk, Wv, Wo, qb);

    // 2) fused Q/K/V projection + RoPE
    gemm_proj_bf16<<<dim3(MM / 128, DATTN / 128, 3), 256, 0, stream>>>(
        qb, kb, vb, wqb, wkb, wvb, Qb, Kb, Vtb);

    // 3) flash attention (TJ=128, XCD-pinned 1-D grid)
    flash_attn_mfma<<<512, 256, 0, stream>>>(Qb, Kb, Vtb, ctx);

    // 4) output GEMM
    gemm_out_bf16<<<dim3(MM / 128, EMB / 128), 256, 0, stream>>>(ctx, wob, out);
}

// Round 14
// 236.873 us; speedup vs baseline: 1.1433x; 1.0482x over previous
//
#include <hip/hip_runtime.h>
#include <hip/hip_bf16.h>

// Problem constants (fixed shapes)
#define BATCH 2
#define SEQ   2048
#define EMB   1024
#define DATTN 1024
#define NH    16
#define HD    64
#define MM    (BATCH*SEQ)        // 4096 rows
#define SCALE 0.03125f           // 1/sqrt(1024), exact power of 2
#define MINIT -1.0e30f
#define ROPE_COEF 0.41524101186f // (2/64)*log2(10000)

using bf16x8 = __attribute__((ext_vector_type(8))) short;   // 8 bf16 (4 VGPRs)
using f32x4  = __attribute__((ext_vector_type(4))) float;   // MFMA C/D

__device__ inline short f2bf(float x) {
    __hip_bfloat16 b = __float2bfloat16(x);
    return *reinterpret_cast<short*>(&b);
}

// async global->LDS, 16 B per lane (wave-uniform LDS base). [m03/m97]
__device__ inline void gl_lds16(const short* g, short* l) {
    __builtin_amdgcn_global_load_lds(
        (const __attribute__((address_space(1))) unsigned int*)g,
        (__attribute__((address_space(3))) unsigned int*)l, 16, 0, 0);
}

// ---------------- fp32 -> bf16 pre-convert (q,k,v,Wq,Wk,Wv,Wo) ----------------
__global__ __launch_bounds__(256)
void cvt_all(const float* __restrict__ q, const float* __restrict__ k,
             const float* __restrict__ v,
             const float* __restrict__ Wq, const float* __restrict__ Wk,
             const float* __restrict__ Wv, const float* __restrict__ Wo,
             short* __restrict__ dst)
{
    const long QKV = (long)MM * EMB;      // 4,194,304
    const long WSZ = (long)DATTN * EMB;   // 1,048,576
    const long i = ((long)blockIdx.x * 256 + threadIdx.x) * 4;
    const float* s;
    long off;
    if (i < 3 * QKV) {
        const int seg = (int)(i / QKV);
        off = i - (long)seg * QKV;
        s = (seg == 0) ? q : (seg == 1) ? k : v;
    } else {
        const long j = i - 3 * QKV;
        const int seg = (int)(j / WSZ);
        off = j - (long)seg * WSZ;
        s = (seg == 0) ? Wq : (seg == 1) ? Wk : (seg == 2) ? Wv : Wo;
    }
    float4 x = *(const float4*)(s + off);
    short4 y;
    y.x = f2bf(x.x); y.y = f2bf(x.y); y.z = f2bf(x.z); y.w = f2bf(x.w);
    *(short4*)(dst + i) = y;
}

// ---------------- bf16 MFMA GEMM: 128x128 tile, BK=32, global_load_lds staging ----------------
__device__ inline void stage_tile(const short* g, short* lds, int wave, int lane) {
    #pragma unroll
    for (int qq = 0; qq < 2; ++qq) {
        const int r = wave * 32 + qq * 16 + (lane >> 2);
        gl_lds16(g + (long)r * EMB + (lane & 3) * 8, lds + (wave * 2 + qq) * 512);
    }
}

// Fused Q/K/V projection with RoPE fused into the epilogue for Q/K.
__global__ __launch_bounds__(256)
void gemm_proj_bf16(const short* __restrict__ qb, const short* __restrict__ kb,
                    const short* __restrict__ vb,
                    const short* __restrict__ wqb, const short* __restrict__ wkb,
                    const short* __restrict__ wvb,
                    short* __restrict__ Qb, short* __restrict__ Kb,
                    short* __restrict__ Vtb)
{
    const short* A; const short* B;
    if (blockIdx.z == 0)      { A = qb; B = wqb; }
    else if (blockIdx.z == 1) { A = kb; B = wkb; }
    else                      { A = vb; B = wvb; }

    __shared__ short sA[128 * 32];
    __shared__ short sB[128 * 32];

    const int tid  = threadIdx.x;
    const int wave = tid >> 6, lane = tid & 63;
    const int quad = lane >> 4, l16 = lane & 15;
    const int wm = (wave >> 1) * 64, wn = (wave & 1) * 64;
    const long m0 = (long)blockIdx.x * 128, n0 = (long)blockIdx.y * 128;

    f32x4 acc[4][4];
    #pragma unroll
    for (int i = 0; i < 4; ++i)
        #pragma unroll
        for (int j = 0; j < 4; ++j) acc[i][j] = (f32x4){0.f, 0.f, 0.f, 0.f};

    for (int kt = 0; kt < EMB; kt += 32) {
        __syncthreads();
        stage_tile(A + m0 * EMB + kt, sA, wave, lane);
        stage_tile(B + n0 * EMB + kt, sB, wave, lane);
        __syncthreads();

        bf16x8 af[4], bfr[4];
        #pragma unroll
        for (int rt = 0; rt < 4; ++rt)
            af[rt] = *(const bf16x8*)&sA[(wm + rt * 16 + l16) * 32 + quad * 8];
        #pragma unroll
        for (int ct = 0; ct < 4; ++ct)
            bfr[ct] = *(const bf16x8*)&sB[(wn + ct * 16 + l16) * 32 + quad * 8];
        #pragma unroll
        for (int rt = 0; rt < 4; ++rt)
            #pragma unroll
            for (int ct = 0; ct < 4; ++ct)
                acc[rt][ct] = __builtin_amdgcn_mfma_f32_16x16x32_bf16(
                    af[rt], bfr[ct], acc[rt][ct], 0, 0, 0);
    }

    if (blockIdx.z < 2) {
        // Q/K: fused RoPE (pair lives in adjacent l16 lanes -> shfl_xor(.,1))
        short* C = (blockIdx.z == 0) ? Qb : Kb;
        const float scl = (blockIdx.z == 0) ? SCALE : 1.0f;
        const int odd = l16 & 1;
        #pragma unroll
        for (int ct = 0; ct < 4; ++ct) {
            const long col = n0 + wn + ct * 16 + l16;
            const int hh = (int)(col >> 6), dd = (int)(col & (HD - 1));
            const float invf = exp2f(-ROPE_COEF * (float)(dd >> 1));
            #pragma unroll
            for (int rt = 0; rt < 4; ++rt) {
                #pragma unroll
                for (int reg = 0; reg < 4; ++reg) {
                    const long row = m0 + wm + rt * 16 + quad * 4 + reg;
                    const int bb = (int)(row >> 11), ss = (int)(row & (SEQ - 1));
                    const float val = acc[rt][ct][reg];
                    const float prt = __shfl_xor(val, 1, 64);
                    float sn, cs;
                    __sincosf((float)ss * invf, &sn, &cs);
                    const float o = odd ? (prt * sn + val * cs)
                                        : (val * cs - prt * sn);
                    C[(((long)(bb * NH + hh)) << 17) + ((long)ss << 6) + dd] =
                        f2bf(o * scl);
                }
            }
        }
    } else {
        // V transposed: Vt[((b*NH+h)*HD + d)*SEQ + s]
        #pragma unroll
        for (int rt = 0; rt < 4; ++rt) {
            #pragma unroll
            for (int ct = 0; ct < 4; ++ct) {
                const long row0 = m0 + wm + rt * 16 + quad * 4;
                const long col  = n0 + wn + ct * 16 + l16;
                const int bb = (int)(row0 >> 11), ss = (int)(row0 & (SEQ - 1));
                const int hh = (int)(col >> 6),   dd = (int)(col & (HD - 1));
                short4 s4;
                s4.x = f2bf(acc[rt][ct][0]); s4.y = f2bf(acc[rt][ct][1]);
                s4.z = f2bf(acc[rt][ct][2]); s4.w = f2bf(acc[rt][ct][3]);
                *(short4*)&Vtb[(((long)(bb * NH + hh)) << 17) + ((long)dd << 11) + ss] = s4;
            }
        }
    }
}

// Output GEMM: out = ctx(bf16) @ Wo^T(bf16), out fp32 [4096,1024]
__global__ __launch_bounds__(256)
void gemm_out_bf16(const short* __restrict__ Ab, const short* __restrict__ Bb,
                   float* __restrict__ C)
{
    __shared__ short sA[128 * 32];
    __shared__ short sB[128 * 32];

    const int tid  = threadIdx.x;
    const int wave = tid >> 6, lane = tid & 63;
    const int quad = lane >> 4, l16 = lane & 15;
    const int wm = (wave >> 1) * 64, wn = (wave & 1) * 64;
    const long m0 = (long)blockIdx.x * 128, n0 = (long)blockIdx.y * 128;

    f32x4 acc[4][4];
    #pragma unroll
    for (int i = 0; i < 4; ++i)
        #pragma unroll
        for (int j = 0; j < 4; ++j) acc[i][j] = (f32x4){0.f, 0.f, 0.f, 0.f};

    for (int kt = 0; kt < DATTN; kt += 32) {
        __syncthreads();
        stage_tile(Ab + m0 * DATTN + kt, sA, wave, lane);
        stage_tile(Bb + n0 * DATTN + kt, sB, wave, lane);
        __syncthreads();

        bf16x8 af[4], bfr[4];
        #pragma unroll
        for (int rt = 0; rt < 4; ++rt)
            af[rt] = *(const bf16x8*)&sA[(wm + rt * 16 + l16) * 32 + quad * 8];
        #pragma unroll
        for (int ct = 0; ct < 4; ++ct)
            bfr[ct] = *(const bf16x8*)&sB[(wn + ct * 16 + l16) * 32 + quad * 8];
        #pragma unroll
        for (int rt = 0; rt < 4; ++rt)
            #pragma unroll
            for (int ct = 0; ct < 4; ++ct)
                acc[rt][ct] = __builtin_amdgcn_mfma_f32_16x16x32_bf16(
                    af[rt], bfr[ct], acc[rt][ct], 0, 0, 0);
    }

    #pragma unroll
    for (int rt = 0; rt < 4; ++rt) {
        #pragma unroll
        for (int ct = 0; ct < 4; ++ct) {
            #pragma unroll
            for (int reg = 0; reg < 4; ++reg) {
                const long row = m0 + wm + rt * 16 + quad * 4 + reg;
                const long col = n0 + wn + ct * 16 + l16;
                C[row * EMB + col] = acc[rt][ct][reg];
            }
        }
    }
}

// ---------------- MFMA flash attention (S^T, TQ=64, TJ=128 staging, XCD-pinned) ----------------
// 1024 blocks; block = (pair p, 64-query tile t). Each of the 4 waves owns ONE
// 16-query group (no serial g loop). XCD pinning: all 32 t-blocks of a pair
// share id%8 -> same XCD -> 512 KB K/V L2-resident (R12-verified: FETCH 55->12 MB).
// LDS 46 KB -> 3 blocks/CU; grid demand 4/CU -> occupancy-filled.
#define LDP 72

__global__ __launch_bounds__(256, 1)
void flash_attn_mfma(const short* __restrict__ Qb,
                     const short* __restrict__ Kb,
                     const short* __restrict__ Vtb,
                     short* __restrict__ ctx)
{
    // id -> (xcd residue r, pair p, query tile t)
    const int id = blockIdx.x;            // 0..1023
    const int r  = id & 7;
    const int q8 = id >> 3;               // 0..127
    const int ts = q8 & 31;               // 32 t-slots
    const int pi = q8 >> 5;               // 4 pairs per residue
    const int p  = r + 8 * pi;            // (b*NH+h) in [0,32)
    const int b  = p >> 4, h = p & 15;
    const int t  = 31 - ts;               // heavy tiles dispatched first
    const int tid = threadIdx.x;
    const int wave = tid >> 6, lane = tid & 63;
    const int quad = lane >> 4, l16 = lane & 15;
    const int r0 = t * 64;

    __shared__ short sk2[2][64 * LDP];
    __shared__ short sv2[2][64 * LDP];
    __shared__ short sp[4][16 * LDP];

    const long base = ((long)(b * NH + h)) << 17;   // SEQ*HD = 2^17

    // Q fragments (B operand): row l16 = query, k = quad*8 (+tt*32)
    const int iq = r0 + wave * 16 + l16;            // this lane's query
    bf16x8 qf[2];
    #pragma unroll
    for (int tt = 0; tt < 2; ++tt)
        qf[tt] = *(const bf16x8*)(Qb + base + (long)iq * HD + tt * 32 + quad * 8);

    f32x4 acc_o[4];
    #pragma unroll
    for (int ct = 0; ct < 4; ++ct) acc_o[ct] = (f32x4){0.f, 0.f, 0.f, 0.f};
    float mq = MINIT, lq = 0.f;

    // key 64-tiles needed: jt2 <= t  ->  128-rounds: ceil((t+1)/2)
    const int njt = (t + 2) >> 1;

    #pragma unroll 1
    for (int jt = 0; jt < njt; ++jt) {
        const int jbase = jt * 128;

        __syncthreads();   // protect previous-iteration sk2/sv2 reads
        #pragma unroll
        for (int c = 0; c < 4; ++c) {
            int cc   = c * 256 + tid;         // 0..1023
            int half = cc >> 9;               // 0..1
            int row  = (cc >> 3) & 63;        // 0..63
            int off  = (cc & 7) * 8;          // 0..56
            int4 tK = *(const int4*)(Kb + base
                + (long)(jbase + half * 64 + row) * HD + off);
            *(int4*)&sk2[half][row * LDP + off] = tK;
            int4 tV = *(const int4*)(Vtb + base
                + ((long)row << 11) + jbase + half * 64 + off);
            *(int4*)&sv2[half][row * LDP + off] = tV;
        }
        __syncthreads();

        #pragma unroll
        for (int half = 0; half < 2; ++half) {
            const int jt2 = 2 * jt + half;    // 64-key tile index
            if (jt2 > t) continue;            // beyond causal range
            const int jb2 = jbase + half * 64;
            const short* skh = sk2[half];
            const short* svh = sv2[half];

            bf16x8 kf[4][2], vf[4][2];
            #pragma unroll
            for (int ct = 0; ct < 4; ++ct) {
                kf[ct][0] = *(const bf16x8*)&skh[(ct * 16 + l16) * LDP + quad * 8];
                kf[ct][1] = *(const bf16x8*)&skh[(ct * 16 + l16) * LDP + 32 + quad * 8];
                vf[ct][0] = *(const bf16x8*)&svh[(ct * 16 + l16) * LDP + quad * 8];
                vf[ct][1] = *(const bf16x8*)&svh[(ct * 16 + l16) * LDP + 32 + quad * 8];
            }

            // S^T: C-layout col=l16=query, row=quad*4+reg=key
            f32x4 s[4];
            #pragma unroll
            for (int ct = 0; ct < 4; ++ct) {
                f32x4 z = (f32x4){0.f, 0.f, 0.f, 0.f};
                z = __builtin_amdgcn_mfma_f32_16x16x32_bf16(kf[ct][0], qf[0], z, 0, 0, 0);
                z = __builtin_amdgcn_mfma_f32_16x16x32_bf16(kf[ct][1], qf[1], z, 0, 0, 0);
                s[ct] = z;
            }

            if (jt2 == t) {   // diagonal tile: apply causal mask
                #pragma unroll
                for (int ct = 0; ct < 4; ++ct)
                    #pragma unroll
                    for (int rr = 0; rr < 4; ++rr) {
                        const int j = jb2 + ct * 16 + quad * 4 + rr;
                        const bool ok = (j < iq) || (iq == 0 && j == 0);
                        if (!ok) s[ct][rr] = -INFINITY;
                    }
            }

            float mx = MINIT;
            #pragma unroll
            for (int ct = 0; ct < 4; ++ct)
                #pragma unroll
                for (int rr = 0; rr < 4; ++rr) mx = fmaxf(mx, s[ct][rr]);
            mx = fmaxf(mx, __shfl_xor(mx, 16, 64));
            mx = fmaxf(mx, __shfl_xor(mx, 32, 64));
            const float mn = fmaxf(mq, mx);
            const float alpha = __expf(mq - mn);
            mq = mn;
            float ss = 0.f;
            #pragma unroll
            for (int ct = 0; ct < 4; ++ct)
                #pragma unroll
                for (int rr = 0; rr < 4; ++rr) {
                    const float e = __expf(s[ct][rr] - mn);
                    s[ct][rr] = e;
                    ss += e;
                }
            ss += __shfl_xor(ss, 16, 64);
            ss += __shfl_xor(ss, 32, 64);
            lq = lq * alpha + ss;

            short* pw = sp[wave];
            #pragma unroll
            for (int ct = 0; ct < 4; ++ct) {
                short4 p4;
                p4.x = f2bf(s[ct][0]); p4.y = f2bf(s[ct][1]);
                p4.z = f2bf(s[ct][2]); p4.w = f2bf(s[ct][3]);
                *(short4*)&pw[l16 * LDP + ct * 16 + quad * 4] = p4;
            }

            #pragma unroll
            for (int ct = 0; ct < 4; ++ct)
                #pragma unroll
                for (int rr = 0; rr < 4; ++rr) acc_o[ct][rr] *= alpha;

            bf16x8 pf0 = *(const bf16x8*)&pw[l16 * LDP + quad * 8];
            bf16x8 pf1 = *(const bf16x8*)&pw[l16 * LDP + 32 + quad * 8];
            #pragma unroll
            for (int ct = 0; ct < 4; ++ct) {
                acc_o[ct] = __builtin_amdgcn_mfma_f32_16x16x32_bf16(
                    vf[ct][0], pf0, acc_o[ct], 0, 0, 0);
                acc_o[ct] = __builtin_amdgcn_mfma_f32_16x16x32_bf16(
                    vf[ct][1], pf1, acc_o[ct], 0, 0, 0);
            }
        }
    }

    // epilogue: acc_o C-layout row=dim (ct*16+quad*4+reg), col=l16=query
    const float inv = 1.f / lq;
    short* orow = ctx + (long)(b * SEQ + iq) * DATTN + h * HD;
    #pragma unroll
    for (int ct = 0; ct < 4; ++ct) {
        short4 o4;
        o4.x = f2bf(acc_o[ct][0] * inv);
        o4.y = f2bf(acc_o[ct][1] * inv);
        o4.z = f2bf(acc_o[ct][2] * inv);
        o4.w = f2bf(acc_o[ct][3] * inv);
        *(short4*)&orow[ct * 16 + quad * 4] = o4;
    }
}

extern "C" void kernel_launch(void* const* d_in, const int* in_sizes, int n_in,
                              void* d_out, int out_size, void* d_ws, size_t ws_size,
                              hipStream_t stream) {
    const float* q  = (const float*)d_in[0];
    const float* k  = (const float*)d_in[1];
    const float* v  = (const float*)d_in[2];
    const float* Wq = (const float*)d_in[3];
    const float* Wk = (const float*)d_in[4];
    const float* Wv = (const float*)d_in[5];
    const float* Wo = (const float*)d_in[6];
    float* out = (float*)d_out;

    // workspace (bf16 shorts), 64 MB:
    // qb|kb|vb (4M shorts each) | wqb|wkb|wvb|wob (1M each) | Qb|Kb|Vtb|ctx (4M each)
    const long QKV = (long)MM * EMB;      // 4,194,304
    const long WSZ = (long)DATTN * EMB;   // 1,048,576
    short* basep = (short*)d_ws;
    short* qb  = basep;
    short* kb  = qb + QKV;
    short* vb  = kb + QKV;
    short* wqb = vb + QKV;
    short* wkb = wqb + WSZ;
    short* wvb = wkb + WSZ;
    short* wob = wvb + WSZ;
    short* Qb  = wob + WSZ;
    short* Kb  = Qb + QKV;
    short* Vtb = Kb + QKV;
    short* ctx = Vtb + QKV;

    // 1) fp32 -> bf16 pre-convert
    cvt_all<<<16384, 256, 0, stream>>>(q, k, v, Wq, Wk, Wv, Wo, qb);

    // 2) fused Q/K/V projection + RoPE
    gemm_proj_bf16<<<dim3(MM / 128, DATTN / 128, 3), 256, 0, stream>>>(
        qb, kb, vb, wqb, wkb, wvb, Qb, Kb, Vtb);

    // 3) flash attention (TQ=64, TJ=128, XCD-pinned 1-D grid)
    flash_attn_mfma<<<1024, 256, 0, stream>>>(Qb, Kb, Vtb, ctx);

    // 4) output GEMM
    gemm_out_bf16<<<dim3(MM / 128, EMB / 128), 256, 0, stream>>>(ctx, wob, out);
}